// Round 5
// baseline (759.512 us; speedup 1.0000x reference)
//
#include <hip/hip_runtime.h>
#include <hip/hip_bf16.h>

#define D 128
#define NPB 16           // nodes per block in fallback logit kernel
#define CHUNK 8192       // edges per bin block
#define BKN 64           // dst nodes per bucket (= accum block)
#define MAXBUCK 1024     // LDS capacity for bucket counters
#define CAP 4096         // accum LDS edge buffer capacity (avg ~1024)

typedef __attribute__((ext_vector_type(8))) short bf16x8;
typedef __attribute__((ext_vector_type(4))) float f32x4;

__device__ __forceinline__ unsigned short f2bf_rne(float f) {
  unsigned u = __float_as_uint(f);
  unsigned r = (u + 0x7FFFu + ((u >> 16) & 1u)) >> 16;
  return (unsigned short)r;
}

__device__ __forceinline__ float fast_tanh(float x) {
  float e = __expf(2.0f * x);
  return 1.0f - 2.0f / (e + 1.0f);
}

// ---------------------------------------------------------------------------
// W1 -> bf16 hi/lo split (one-time, 16384 elements)
// ---------------------------------------------------------------------------
__global__ __launch_bounds__(256) void w1_convert_kernel(
    const float* __restrict__ W1, unsigned short* __restrict__ w1hi,
    unsigned short* __restrict__ w1lo) {
  int i = blockIdx.x * 256 + threadIdx.x;
  float x = W1[i];
  unsigned short h = f2bf_rne(x);
  float hf = __uint_as_float((unsigned)h << 16);
  w1hi[i] = h;
  w1lo[i] = f2bf_rne(x - hf);
}

// ---------------------------------------------------------------------------
// explog[i] = exp(logit[i])
// ---------------------------------------------------------------------------
__global__ __launch_bounds__(256) void exp_kernel(
    const float* __restrict__ logit, float* __restrict__ explog, int n) {
  int i = blockIdx.x * 256 + threadIdx.x;
  if (i < n) explog[i] = expf(logit[i]);
}

// ---------------------------------------------------------------------------
// logit via split-bf16 MFMA (R3-verified) + FUSED N->bf16 export.
// nbf layout is pair-permuted: u32 slot l of a row = (feature l | feature
// l+64 << 16)  -> accum does ONE u32 gather per lane and conflict-free LDS
// adds at byte offsets 4l and 256+4l.
// ---------------------------------------------------------------------------
__global__ __launch_bounds__(256, 2) void logit_mfma_kernel(
    const float* __restrict__ Nm, const unsigned short* __restrict__ w1hi,
    const unsigned short* __restrict__ w1lo, const float* __restrict__ w2,
    float* __restrict__ logit, unsigned short* __restrict__ nbf, int n_nodes) {
  __shared__ unsigned short lhi[64 * 128];
  __shared__ unsigned short llo[64 * 128];
  const int tid = threadIdx.x;
  const int w = tid >> 6;
  const int l = tid & 63;
  const int lg = l >> 4;
  const int ln = l & 15;
  const int base = blockIdx.x * 64;

  bf16x8 Bh[2][4], Bl[2][4];
#pragma unroll
  for (int ntl = 0; ntl < 2; ++ntl) {
    int n = (w * 2 + ntl) * 16 + ln;
#pragma unroll
    for (int kt = 0; kt < 4; ++kt) {
      int k = kt * 32 + lg * 8;
      Bh[ntl][kt] = *(const bf16x8*)(w1hi + n * 128 + k);
      Bl[ntl][kt] = *(const bf16x8*)(w1lo + n * 128 + k);
    }
  }

#pragma unroll
  for (int i = 0; i < 8; ++i) {
    int flat = tid + i * 256;
    int row = flat >> 5;
    int c4 = flat & 31;
    int grow = base + row;
    if (grow >= n_nodes) grow = n_nodes - 1;
    float4 v = *(const float4*)(Nm + (size_t)grow * D + c4 * 4);
    unsigned short h0 = f2bf_rne(v.x), h1 = f2bf_rne(v.y);
    unsigned short h2 = f2bf_rne(v.z), h3 = f2bf_rne(v.w);
    unsigned short o0 = f2bf_rne(v.x - __uint_as_float((unsigned)h0 << 16));
    unsigned short o1 = f2bf_rne(v.y - __uint_as_float((unsigned)h1 << 16));
    unsigned short o2 = f2bf_rne(v.z - __uint_as_float((unsigned)h2 << 16));
    unsigned short o3 = f2bf_rne(v.w - __uint_as_float((unsigned)h3 << 16));
    int boff = (c4 * 8) ^ ((row & 7) << 4);
    *(ushort4*)((char*)lhi + row * 256 + boff) = make_ushort4(h0, h1, h2, h3);
    *(ushort4*)((char*)llo + row * 256 + boff) = make_ushort4(o0, o1, o2, o3);
    // fused nbf export (pair-permuted): feature f -> slot (f<64 ? 2f : 2(f-64)+1)
    unsigned short hv0 = h0, hv1 = h1, hv2 = h2, hv3 = h3;
    int f0 = c4 * 4;
    unsigned short* nrow = nbf + (size_t)grow * D;
#pragma unroll
    for (int q = 0; q < 4; ++q) {
      int f = f0 + q;
      int pos = (f < 64) ? (f << 1) : (((f - 64) << 1) | 1);
      unsigned short hv = (q == 0) ? hv0 : (q == 1) ? hv1 : (q == 2) ? hv2 : hv3;
      nrow[pos] = hv;
    }
  }
  __syncthreads();

  f32x4 acc[4][2];
#pragma unroll
  for (int mt = 0; mt < 4; ++mt)
#pragma unroll
    for (int ntl = 0; ntl < 2; ++ntl) acc[mt][ntl] = (f32x4){0.f, 0.f, 0.f, 0.f};

#pragma unroll
  for (int mt = 0; mt < 4; ++mt) {
    int row = mt * 16 + ln;
    bf16x8 Ah[4], Al[4];
#pragma unroll
    for (int kt = 0; kt < 4; ++kt) {
      int boff = (kt * 64 + lg * 16) ^ ((row & 7) << 4);
      Ah[kt] = *(const bf16x8*)((const char*)lhi + row * 256 + boff);
      Al[kt] = *(const bf16x8*)((const char*)llo + row * 256 + boff);
    }
#pragma unroll
    for (int ntl = 0; ntl < 2; ++ntl) {
#pragma unroll
      for (int kt = 0; kt < 4; ++kt) {
        acc[mt][ntl] = __builtin_amdgcn_mfma_f32_16x16x32_bf16(
            Ah[kt], Bh[ntl][kt], acc[mt][ntl], 0, 0, 0);
        acc[mt][ntl] = __builtin_amdgcn_mfma_f32_16x16x32_bf16(
            Ah[kt], Bl[ntl][kt], acc[mt][ntl], 0, 0, 0);
        acc[mt][ntl] = __builtin_amdgcn_mfma_f32_16x16x32_bf16(
            Al[kt], Bh[ntl][kt], acc[mt][ntl], 0, 0, 0);
      }
    }
  }

  float w2a = w2[(w * 2 + 0) * 16 + ln];
  float w2b = w2[(w * 2 + 1) * 16 + ln];
#pragma unroll
  for (int mt = 0; mt < 4; ++mt) {
    float s0 = fast_tanh(acc[mt][0][0]) * w2a + fast_tanh(acc[mt][1][0]) * w2b;
    float s1 = fast_tanh(acc[mt][0][1]) * w2a + fast_tanh(acc[mt][1][1]) * w2b;
    float s2 = fast_tanh(acc[mt][0][2]) * w2a + fast_tanh(acc[mt][1][2]) * w2b;
    float s3 = fast_tanh(acc[mt][0][3]) * w2a + fast_tanh(acc[mt][1][3]) * w2b;
#pragma unroll
    for (int mask = 1; mask < 16; mask <<= 1) {
      s0 += __shfl_xor(s0, mask);
      s1 += __shfl_xor(s1, mask);
      s2 += __shfl_xor(s2, mask);
      s3 += __shfl_xor(s3, mask);
    }
    if (ln < 4) {
      float sv = (ln == 0) ? s0 : (ln == 1) ? s1 : (ln == 2) ? s2 : s3;
      int node = base + mt * 16 + lg * 4 + ln;
      if (node < n_nodes) atomicAdd(&logit[node], sv);
    }
  }
}

// ---------------------------------------------------------------------------
// Bin kernel: LDS counting-sort of a CHUNK of edges by bucket (dst>>6).
// Output: binout[blk*CHUNK ...] = packed (src | (dst&63)<<16), bucket-ordered,
// written fully coalesced; dir[blk][k] = u16 start of bucket k's run.
// ---------------------------------------------------------------------------
__global__ __launch_bounds__(256) void bin_kernel(
    const int* __restrict__ src, const int* __restrict__ dst,
    unsigned* __restrict__ binout, unsigned short* __restrict__ dir,
    int n_edges, int nbuck) {
  __shared__ unsigned cnt[MAXBUCK];
  __shared__ unsigned cur[MAXBUCK];
  __shared__ unsigned ebuf[CHUNK];
  __shared__ int sdata[256];
  const int tid = threadIdx.x;
  const int blk = blockIdx.x;
  const int ebase = blk * CHUNK;
  const int chunkN = min(CHUNK, n_edges - ebase);

  for (int i = tid; i < MAXBUCK; i += 256) cnt[i] = 0;
  __syncthreads();

  // phase 1: count
  for (int i = tid; i < chunkN; i += 256) {
    int d = dst[ebase + i];
    atomicAdd(&cnt[d >> 6], 1u);
  }
  __syncthreads();

  // phase 2: exclusive scan over MAXBUCK (padded zeros), 4 elems/thread
  int t4 = tid * 4;
  int c0 = cnt[t4], c1 = cnt[t4 + 1], c2 = cnt[t4 + 2], c3 = cnt[t4 + 3];
  int s = c0 + c1 + c2 + c3;
  sdata[tid] = s;
  __syncthreads();
  for (int d = 1; d < 256; d <<= 1) {
    int v = (tid >= d) ? sdata[tid - d] : 0;
    __syncthreads();
    sdata[tid] += v;
    __syncthreads();
  }
  int tb = sdata[tid] - s;
  cur[t4] = tb;
  cur[t4 + 1] = tb + c0;
  cur[t4 + 2] = tb + c0 + c1;
  cur[t4 + 3] = tb + c0 + c1 + c2;
  __syncthreads();

  // write directory (starts + total)
  size_t dbase = (size_t)blk * (nbuck + 1);
  for (int k = tid; k < nbuck; k += 256) dir[dbase + k] = (unsigned short)cur[k];
  if (tid == 0) dir[dbase + nbuck] = (unsigned short)chunkN;
  __syncthreads();

  // phase 3: place into LDS (consumes cur)
  for (int i = tid; i < chunkN; i += 256) {
    int d = dst[ebase + i];
    int sv = src[ebase + i];
    unsigned slot = atomicAdd(&cur[d >> 6], 1u);
    ebuf[slot] = (unsigned)sv | ((unsigned)(d & 63) << 16);
  }
  __syncthreads();

  // phase 4: coalesced flush
  for (int i = tid; i < chunkN; i += 256) binout[ebase + i] = ebuf[i];
}

// ---------------------------------------------------------------------------
// Accum: one block per 64-node bucket. Gather runs from all bin chunks into
// LDS, then process edges 4-wide per wave into LDS f32 accumulators.
// Output written once, coalesced. Denominator accumulated in-pass.
// ---------------------------------------------------------------------------
__global__ __launch_bounds__(256) void accum_lds_kernel(
    const unsigned* __restrict__ binout, const unsigned short* __restrict__ dir,
    const float* __restrict__ explog, const unsigned* __restrict__ nbf32,
    float* __restrict__ out, int n_nodes, int nbuck, int nblk_bin) {
  __shared__ float facc[BKN][128];
  __shared__ float fden[BKN];
  __shared__ unsigned ebuf[CAP];
  __shared__ int total;
  const int tid = threadIdx.x;
  const int w = tid >> 6;
  const int lane = tid & 63;
  const int bk = blockIdx.x;

  for (int i = tid; i < BKN * 128; i += 256) ((float*)facc)[i] = 0.f;
  if (tid < BKN) fden[tid] = 0.f;
  if (tid == 0) total = 0;
  __syncthreads();

  // stage A: copy this bucket's runs (from each bin chunk) into LDS
  for (int r = w; r < nblk_bin; r += 4) {
    size_t dbase = (size_t)r * (nbuck + 1);
    int s0 = dir[dbase + bk];
    int s1 = dir[dbase + bk + 1];
    int len = s1 - s0;
    if (len <= 0) continue;
    int pos = 0;
    if (lane == 0) pos = atomicAdd(&total, len);
    pos = __shfl(pos, 0);
    if (pos + len > CAP) len = (CAP > pos) ? (CAP - pos) : 0;  // paranoia
    const unsigned* g = binout + (size_t)r * CHUNK + s0;
    for (int i = lane; i < len; i += 64) ebuf[pos + i] = g[i];
  }
  __syncthreads();
  int tot = total;
  if (tot > CAP) tot = CAP;

  // stage B: process edges, 4 per wave-iteration for gather MLP
  for (int base = w * 4; base < tot; base += 16) {
    if (base + 4 <= tot) {
      unsigned p0 = ebuf[base + 0], p1 = ebuf[base + 1];
      unsigned p2 = ebuf[base + 2], p3 = ebuf[base + 3];
      int s0 = p0 & 0xFFFF, s1 = p1 & 0xFFFF, s2 = p2 & 0xFFFF, s3 = p3 & 0xFFFF;
      int d0 = p0 >> 16, d1 = p1 >> 16, d2 = p2 >> 16, d3 = p3 >> 16;
      float x0 = explog[s0], x1 = explog[s1], x2 = explog[s2], x3 = explog[s3];
      unsigned u0 = nbf32[(size_t)s0 * 64 + lane];
      unsigned u1 = nbf32[(size_t)s1 * 64 + lane];
      unsigned u2 = nbf32[(size_t)s2 * 64 + lane];
      unsigned u3 = nbf32[(size_t)s3 * 64 + lane];
      atomicAdd(&facc[d0][lane], x0 * __uint_as_float(u0 << 16));
      atomicAdd(&facc[d0][lane + 64], x0 * __uint_as_float(u0 & 0xFFFF0000u));
      atomicAdd(&facc[d1][lane], x1 * __uint_as_float(u1 << 16));
      atomicAdd(&facc[d1][lane + 64], x1 * __uint_as_float(u1 & 0xFFFF0000u));
      atomicAdd(&facc[d2][lane], x2 * __uint_as_float(u2 << 16));
      atomicAdd(&facc[d2][lane + 64], x2 * __uint_as_float(u2 & 0xFFFF0000u));
      atomicAdd(&facc[d3][lane], x3 * __uint_as_float(u3 << 16));
      atomicAdd(&facc[d3][lane + 64], x3 * __uint_as_float(u3 & 0xFFFF0000u));
      if (lane == 0) {
        atomicAdd(&fden[d0], x0);
        atomicAdd(&fden[d1], x1);
        atomicAdd(&fden[d2], x2);
        atomicAdd(&fden[d3], x3);
      }
    } else {
      for (int j = 0; j < tot - base; ++j) {
        unsigned p = ebuf[base + j];
        int sj = p & 0xFFFF;
        int dj = p >> 16;
        float x = explog[sj];
        unsigned u = nbf32[(size_t)sj * 64 + lane];
        atomicAdd(&facc[dj][lane], x * __uint_as_float(u << 16));
        atomicAdd(&facc[dj][lane + 64], x * __uint_as_float(u & 0xFFFF0000u));
        if (lane == 0) atomicAdd(&fden[dj], x);
      }
    }
  }
  __syncthreads();

  // epilogue: invert denominators, write rows coalesced
  if (tid < BKN) fden[tid] = (fden[tid] > 0.f) ? 1.0f / fden[tid] : 0.f;
  __syncthreads();
  int node0 = bk * BKN;
  for (int i = tid; i < BKN * 128; i += 256) {
    int r = i >> 7, f = i & 127;
    int node = node0 + r;
    if (node < n_nodes) out[(size_t)node * D + f] = facc[r][f] * fden[r];
  }
}

// ---------------------------------------------------------------------------
// Fallback path: scalar logit + per-edge atomics (R1, verified)
// ---------------------------------------------------------------------------
__global__ __launch_bounds__(256) void logit_kernel(
    const float* __restrict__ Nm, const float* __restrict__ W1,
    const float* __restrict__ w2, float* __restrict__ logit, int n_nodes) {
  __shared__ float w1t[32 * 129];
  const int tid = threadIdx.x;
  const int j = tid & 127;
  const int half = tid >> 7;
  const int base = blockIdx.x * NPB;
  float acc[8];
#pragma unroll
  for (int g = 0; g < 8; ++g) acc[g] = 0.f;
  for (int c = 0; c < 4; ++c) {
    __syncthreads();
    for (int idx = tid; idx < 128 * 32; idx += 256) {
      int kl = idx & 31, jj = idx >> 5;
      w1t[kl * 129 + jj] = W1[jj * 128 + c * 32 + kl];
    }
    __syncthreads();
#pragma unroll
    for (int g = 0; g < 8; ++g) {
      int node = base + g * 2 + half;
      if (node < n_nodes) {
        const float4* nrow =
            reinterpret_cast<const float4*>(Nm + (size_t)node * D + c * 32);
        float a = acc[g];
#pragma unroll
        for (int k4 = 0; k4 < 8; ++k4) {
          float4 nv = nrow[k4];
          int kl = k4 * 4;
          a += nv.x * w1t[(kl + 0) * 129 + j];
          a += nv.y * w1t[(kl + 1) * 129 + j];
          a += nv.z * w1t[(kl + 2) * 129 + j];
          a += nv.w * w1t[(kl + 3) * 129 + j];
        }
        acc[g] = a;
      }
    }
  }
  const float w2j = w2[j];
#pragma unroll
  for (int g = 0; g < 8; ++g) {
    int node = base + g * 2 + half;
    float t = tanhf(acc[g]) * w2j;
#pragma unroll
    for (int off = 32; off; off >>= 1) t += __shfl_down(t, off);
    if ((tid & 63) == 0 && node < n_nodes) atomicAdd(&logit[node], t);
  }
}

__global__ __launch_bounds__(256) void denom_kernel(
    const int* __restrict__ src, const int* __restrict__ dst,
    const float* __restrict__ logit, float* __restrict__ denom, int n_edges) {
  int e = blockIdx.x * 256 + threadIdx.x;
  if (e < n_edges) {
    float ex = expf(logit[src[e]]);
    atomicAdd(&denom[dst[e]], ex);
  }
}

__global__ __launch_bounds__(256) void scatter_kernel(
    const int* __restrict__ src, const int* __restrict__ dst,
    const float* __restrict__ logit, const float* __restrict__ denom,
    const float* __restrict__ Nm, float* __restrict__ out, int n_edges) {
  int wave = (blockIdx.x * 256 + threadIdx.x) >> 6;
  int lane = threadIdx.x & 63;
  if (wave >= n_edges) return;
  int s = src[wave];
  int d = dst[wave];
  float a = expf(logit[s]) / denom[d];
  float v0 = Nm[(size_t)s * D + lane];
  float v1 = Nm[(size_t)s * D + 64 + lane];
  atomicAdd(&out[(size_t)d * D + lane], a * v0);
  atomicAdd(&out[(size_t)d * D + 64 + lane], a * v1);
}

static inline char* align_up(char* p, size_t a) {
  return (char*)(((uintptr_t)p + a - 1) & ~(uintptr_t)(a - 1));
}

extern "C" void kernel_launch(void* const* d_in, const int* in_sizes, int n_in,
                              void* d_out, int out_size, void* d_ws,
                              size_t ws_size, hipStream_t stream) {
  const float* Nm  = (const float*)d_in[0];
  const float* W1  = (const float*)d_in[1];
  const float* w2  = (const float*)d_in[2];
  const int*   src = (const int*)d_in[3];
  const int*   dst = (const int*)d_in[4];
  float* out = (float*)d_out;

  const int n_nodes = in_sizes[0] / D;
  const int n_edges = in_sizes[3];
  const int n_pad = (n_nodes + 63) & ~63;
  const int nbuck = (n_nodes + BKN - 1) / BKN;
  const int nblk_bin = (n_edges + CHUNK - 1) / CHUNK;

  // carve workspace
  char* p = (char*)d_ws;
  float* logit  = (float*)p;     p = align_up(p + (size_t)n_pad * 4, 256);
  float* explog = (float*)p;     p = align_up(p + (size_t)n_pad * 4, 256);
  unsigned short* w1hi = (unsigned short*)p; p = align_up(p + 128 * 128 * 2, 256);
  unsigned short* w1lo = (unsigned short*)p; p = align_up(p + 128 * 128 * 2, 256);
  unsigned short* nbf = (unsigned short*)p;
  p = align_up(p + (size_t)n_nodes * D * 2, 256);
  unsigned* binout = (unsigned*)p;
  p = align_up(p + (size_t)nblk_bin * CHUNK * 4, 256);
  unsigned short* dir = (unsigned short*)p;
  p = align_up(p + (size_t)nblk_bin * (nbuck + 1) * 2, 256);
  size_t needed = (size_t)(p - (char*)d_ws);

  hipMemsetAsync(logit, 0, (size_t)n_pad * sizeof(float), stream);

  const bool fits = (ws_size >= needed) && (n_nodes <= 65535) &&
                    (nbuck <= MAXBUCK) && (n_edges / nbuck < CAP / 3);

  if (fits) {
    // logit chain (writes nbf as fused side-product)
    w1_convert_kernel<<<64, 256, 0, stream>>>(W1, w1hi, w1lo);
    int nblk1 = (n_nodes + 63) / 64;
    logit_mfma_kernel<<<nblk1, 256, 0, stream>>>(Nm, w1hi, w1lo, w2, logit,
                                                 nbf, n_nodes);
    int nblkE = (n_nodes + 255) / 256;
    exp_kernel<<<nblkE, 256, 0, stream>>>(logit, explog, n_nodes);

    // edge sort (bucket-level) — independent of logit chain
    bin_kernel<<<nblk_bin, 256, 0, stream>>>(src, dst, binout, dir, n_edges,
                                             nbuck);

    // bucket accumulation
    accum_lds_kernel<<<nbuck, 256, 0, stream>>>(
        binout, dir, explog, (const unsigned*)nbf, out, n_nodes, nbuck,
        nblk_bin);
  } else {
    // fallback: scalar logit + R1 atomic path
    int nblk1 = (n_nodes + NPB - 1) / NPB;
    logit_kernel<<<nblk1, 256, 0, stream>>>(Nm, W1, w2, logit, n_nodes);
    float* denom = logit + n_pad;
    hipMemsetAsync(denom, 0, (size_t)n_pad * sizeof(float), stream);
    hipMemsetAsync(out, 0, (size_t)out_size * sizeof(float), stream);
    int eblk = (n_edges + 255) / 256;
    denom_kernel<<<eblk, 256, 0, stream>>>(src, dst, logit, denom, n_edges);
    int nblk3 = (n_edges + 3) / 4;
    scatter_kernel<<<nblk3, 256, 0, stream>>>(src, dst, logit, denom, Nm, out,
                                              n_edges);
  }
}

// Round 6
// 130.184 us; speedup vs baseline: 5.8342x; 5.8342x over previous
//
#include <hip/hip_runtime.h>
#include <hip/hip_bf16.h>

#define D 128
#define NPB 16           // nodes per block in fallback logit kernel
#define CHUNK 8192       // edges per bin block
#define BKN 64           // dst nodes per bucket
#define MAXBUCK 1024     // max buckets (also bscan block size)
#define NCHUNK_MAX 128   // max bin chunks supported by merge
#define CAP 4096         // merge LDS edge buffer (avg bucket ~1024)

typedef __attribute__((ext_vector_type(8))) short bf16x8;
typedef __attribute__((ext_vector_type(4))) float f32x4;

__device__ __forceinline__ unsigned short f2bf_rne(float f) {
  unsigned u = __float_as_uint(f);
  unsigned r = (u + 0x7FFFu + ((u >> 16) & 1u)) >> 16;
  return (unsigned short)r;
}

__device__ __forceinline__ float fast_tanh(float x) {
  float e = __expf(2.0f * x);
  return 1.0f - 2.0f / (e + 1.0f);
}

// ---------------------------------------------------------------------------
// W1 -> bf16 hi/lo split
// ---------------------------------------------------------------------------
__global__ __launch_bounds__(256) void w1_convert_kernel(
    const float* __restrict__ W1, unsigned short* __restrict__ w1hi,
    unsigned short* __restrict__ w1lo) {
  int i = blockIdx.x * 256 + threadIdx.x;
  float x = W1[i];
  unsigned short h = f2bf_rne(x);
  float hf = __uint_as_float((unsigned)h << 16);
  w1hi[i] = h;
  w1lo[i] = f2bf_rne(x - hf);
}

__global__ __launch_bounds__(256) void exp_kernel(
    const float* __restrict__ logit, float* __restrict__ explog, int n) {
  int i = blockIdx.x * 256 + threadIdx.x;
  if (i < n) explog[i] = expf(logit[i]);
}

// ---------------------------------------------------------------------------
// logit via split-bf16 MFMA (R3-verified) + fused N->bf16 export (PLAIN row
// layout: nbf[node*128 + f]); accum reads u32 at node*64+lane = features
// (2*lane, 2*lane+1).
// ---------------------------------------------------------------------------
__global__ __launch_bounds__(256, 2) void logit_mfma_kernel(
    const float* __restrict__ Nm, const unsigned short* __restrict__ w1hi,
    const unsigned short* __restrict__ w1lo, const float* __restrict__ w2,
    float* __restrict__ logit, unsigned short* __restrict__ nbf, int n_nodes) {
  __shared__ unsigned short lhi[64 * 128];
  __shared__ unsigned short llo[64 * 128];
  const int tid = threadIdx.x;
  const int w = tid >> 6;
  const int l = tid & 63;
  const int lg = l >> 4;
  const int ln = l & 15;
  const int base = blockIdx.x * 64;

  bf16x8 Bh[2][4], Bl[2][4];
#pragma unroll
  for (int ntl = 0; ntl < 2; ++ntl) {
    int n = (w * 2 + ntl) * 16 + ln;
#pragma unroll
    for (int kt = 0; kt < 4; ++kt) {
      int k = kt * 32 + lg * 8;
      Bh[ntl][kt] = *(const bf16x8*)(w1hi + n * 128 + k);
      Bl[ntl][kt] = *(const bf16x8*)(w1lo + n * 128 + k);
    }
  }

#pragma unroll
  for (int i = 0; i < 8; ++i) {
    int flat = tid + i * 256;
    int row = flat >> 5;
    int c4 = flat & 31;
    int grow = base + row;
    if (grow >= n_nodes) grow = n_nodes - 1;
    float4 v = *(const float4*)(Nm + (size_t)grow * D + c4 * 4);
    unsigned short h0 = f2bf_rne(v.x), h1 = f2bf_rne(v.y);
    unsigned short h2 = f2bf_rne(v.z), h3 = f2bf_rne(v.w);
    unsigned short o0 = f2bf_rne(v.x - __uint_as_float((unsigned)h0 << 16));
    unsigned short o1 = f2bf_rne(v.y - __uint_as_float((unsigned)h1 << 16));
    unsigned short o2 = f2bf_rne(v.z - __uint_as_float((unsigned)h2 << 16));
    unsigned short o3 = f2bf_rne(v.w - __uint_as_float((unsigned)h3 << 16));
    int boff = (c4 * 8) ^ ((row & 7) << 4);
    *(ushort4*)((char*)lhi + row * 256 + boff) = make_ushort4(h0, h1, h2, h3);
    *(ushort4*)((char*)llo + row * 256 + boff) = make_ushort4(o0, o1, o2, o3);
    // fused bf16 export, plain layout, one 8B store
    *(ushort4*)(nbf + (size_t)grow * D + c4 * 4) =
        make_ushort4(h0, h1, h2, h3);
  }
  __syncthreads();

  f32x4 acc[4][2];
#pragma unroll
  for (int mt = 0; mt < 4; ++mt)
#pragma unroll
    for (int ntl = 0; ntl < 2; ++ntl) acc[mt][ntl] = (f32x4){0.f, 0.f, 0.f, 0.f};

#pragma unroll
  for (int mt = 0; mt < 4; ++mt) {
    int row = mt * 16 + ln;
    bf16x8 Ah[4], Al[4];
#pragma unroll
    for (int kt = 0; kt < 4; ++kt) {
      int boff = (kt * 64 + lg * 16) ^ ((row & 7) << 4);
      Ah[kt] = *(const bf16x8*)((const char*)lhi + row * 256 + boff);
      Al[kt] = *(const bf16x8*)((const char*)llo + row * 256 + boff);
    }
#pragma unroll
    for (int ntl = 0; ntl < 2; ++ntl) {
#pragma unroll
      for (int kt = 0; kt < 4; ++kt) {
        acc[mt][ntl] = __builtin_amdgcn_mfma_f32_16x16x32_bf16(
            Ah[kt], Bh[ntl][kt], acc[mt][ntl], 0, 0, 0);
        acc[mt][ntl] = __builtin_amdgcn_mfma_f32_16x16x32_bf16(
            Ah[kt], Bl[ntl][kt], acc[mt][ntl], 0, 0, 0);
        acc[mt][ntl] = __builtin_amdgcn_mfma_f32_16x16x32_bf16(
            Al[kt], Bh[ntl][kt], acc[mt][ntl], 0, 0, 0);
      }
    }
  }

  float w2a = w2[(w * 2 + 0) * 16 + ln];
  float w2b = w2[(w * 2 + 1) * 16 + ln];
#pragma unroll
  for (int mt = 0; mt < 4; ++mt) {
    float s0 = fast_tanh(acc[mt][0][0]) * w2a + fast_tanh(acc[mt][1][0]) * w2b;
    float s1 = fast_tanh(acc[mt][0][1]) * w2a + fast_tanh(acc[mt][1][1]) * w2b;
    float s2 = fast_tanh(acc[mt][0][2]) * w2a + fast_tanh(acc[mt][1][2]) * w2b;
    float s3 = fast_tanh(acc[mt][0][3]) * w2a + fast_tanh(acc[mt][1][3]) * w2b;
#pragma unroll
    for (int mask = 1; mask < 16; mask <<= 1) {
      s0 += __shfl_xor(s0, mask);
      s1 += __shfl_xor(s1, mask);
      s2 += __shfl_xor(s2, mask);
      s3 += __shfl_xor(s3, mask);
    }
    if (ln < 4) {
      float sv = (ln == 0) ? s0 : (ln == 1) ? s1 : (ln == 2) ? s2 : s3;
      int node = base + mt * 16 + lg * 4 + ln;
      if (node < n_nodes) atomicAdd(&logit[node], sv);
    }
  }
}

// ---------------------------------------------------------------------------
// Bin: chunk-local LDS counting sort by bucket (dst>>6); coalesced output.
// binout entry = src | (dst&63)<<16 ; dir[blk][k] = run start (u16).
// ---------------------------------------------------------------------------
__global__ __launch_bounds__(256) void bin_kernel(
    const int* __restrict__ src, const int* __restrict__ dst,
    unsigned* __restrict__ binout, unsigned short* __restrict__ dir,
    int n_edges, int nbuck) {
  __shared__ unsigned cnt[MAXBUCK];
  __shared__ unsigned cur[MAXBUCK];
  __shared__ unsigned ebuf[CHUNK];
  __shared__ int sdata[256];
  const int tid = threadIdx.x;
  const int blk = blockIdx.x;
  const int ebase = blk * CHUNK;
  const int chunkN = min(CHUNK, n_edges - ebase);

  for (int i = tid; i < MAXBUCK; i += 256) cnt[i] = 0;
  __syncthreads();

  for (int i = tid; i < chunkN; i += 256) {
    int d = dst[ebase + i];
    atomicAdd(&cnt[d >> 6], 1u);
  }
  __syncthreads();

  int t4 = tid * 4;
  int c0 = cnt[t4], c1 = cnt[t4 + 1], c2 = cnt[t4 + 2], c3 = cnt[t4 + 3];
  int s = c0 + c1 + c2 + c3;
  sdata[tid] = s;
  __syncthreads();
  for (int d = 1; d < 256; d <<= 1) {
    int v = (tid >= d) ? sdata[tid - d] : 0;
    __syncthreads();
    sdata[tid] += v;
    __syncthreads();
  }
  int tb = sdata[tid] - s;
  cur[t4] = tb;
  cur[t4 + 1] = tb + c0;
  cur[t4 + 2] = tb + c0 + c1;
  cur[t4 + 3] = tb + c0 + c1 + c2;
  __syncthreads();

  size_t dbase = (size_t)blk * (nbuck + 1);
  for (int k = tid; k < nbuck; k += 256) dir[dbase + k] = (unsigned short)cur[k];
  if (tid == 0) dir[dbase + nbuck] = (unsigned short)chunkN;
  __syncthreads();

  for (int i = tid; i < chunkN; i += 256) {
    int d = dst[ebase + i];
    int sv = src[ebase + i];
    unsigned slot = atomicAdd(&cur[d >> 6], 1u);
    ebuf[slot] = (unsigned)sv | ((unsigned)(d & 63) << 16);
  }
  __syncthreads();

  for (int i = tid; i < chunkN; i += 256) binout[ebase + i] = ebuf[i];
}

// ---------------------------------------------------------------------------
// Bucket totals and exclusive scan -> global bucket bases
// ---------------------------------------------------------------------------
__global__ __launch_bounds__(256) void btot_kernel(
    const unsigned short* __restrict__ dir, int* __restrict__ blen, int nbuck,
    int nblk_bin) {
  int bk = blockIdx.x * 256 + threadIdx.x;
  if (bk >= nbuck) return;
  int s = 0;
  for (int r = 0; r < nblk_bin; ++r) {
    size_t dbase = (size_t)r * (nbuck + 1);
    s += (int)dir[dbase + bk + 1] - (int)dir[dbase + bk];
  }
  blen[bk] = s;
}

__global__ __launch_bounds__(1024) void bscan_kernel(
    const int* __restrict__ blen, int* __restrict__ bbase, int nbuck) {
  __shared__ int sdata[1024];
  int tid = threadIdx.x;
  int v = (tid < nbuck) ? blen[tid] : 0;
  sdata[tid] = v;
  __syncthreads();
  for (int d = 1; d < 1024; d <<= 1) {
    int t = (tid >= d) ? sdata[tid - d] : 0;
    __syncthreads();
    sdata[tid] += t;
    __syncthreads();
  }
  if (tid < nbuck) bbase[tid] = sdata[tid] - v;
}

// ---------------------------------------------------------------------------
// Merge: one block per bucket. Gather this bucket's runs (deterministic
// placement via per-chunk scan), counting-sort by dst&63, write the fully
// dst-sorted edge array (private ~4KB window -> no line bounce) + CSR offsets.
// ---------------------------------------------------------------------------
__global__ __launch_bounds__(256) void merge_kernel(
    const unsigned* __restrict__ binout, const unsigned short* __restrict__ dir,
    const int* __restrict__ bbase, unsigned* __restrict__ sorted,
    int* __restrict__ offsets, int n_nodes, int nbuck, int nblk_bin,
    int n_edges) {
  __shared__ unsigned ebuf[CAP];
  __shared__ int lens[NCHUNK_MAX], cstart[NCHUNK_MAX], ls0[NCHUNK_MAX];
  __shared__ int cnt[BKN], nstart[BKN + 1], cur[BKN];
  __shared__ int total;
  const int tid = threadIdx.x;
  const int w = tid >> 6, lane = tid & 63;
  const int bk = blockIdx.x;
  const int node0 = bk * BKN;

  if (tid < nblk_bin) {
    size_t dbase = (size_t)tid * (nbuck + 1);
    int s0 = dir[dbase + bk];
    int s1 = dir[dbase + bk + 1];
    ls0[tid] = s0;
    lens[tid] = s1 - s0;
  }
  if (tid < BKN) cnt[tid] = 0;
  __syncthreads();
  if (tid == 0) {
    int run = 0;
    for (int r = 0; r < nblk_bin; ++r) {
      cstart[r] = run;
      run += lens[r];
    }
    total = (run > CAP) ? CAP : run;
  }
  __syncthreads();
  const int tot = total;

  for (int r = w; r < nblk_bin; r += 4) {
    int len = lens[r], cs = cstart[r];
    if (cs >= CAP) continue;
    if (cs + len > CAP) len = CAP - cs;
    const unsigned* g = binout + (size_t)r * CHUNK + ls0[r];
    for (int i = lane; i < len; i += 64) ebuf[cs + i] = g[i];
  }
  __syncthreads();

  for (int i = tid; i < tot; i += 256) atomicAdd(&cnt[ebuf[i] >> 16], 1);
  __syncthreads();
  if (tid == 0) {
    int run = 0;
    for (int t = 0; t < BKN; ++t) {
      nstart[t] = run;
      run += cnt[t];
    }
    nstart[BKN] = run;
  }
  __syncthreads();

  const int base = bbase[bk];
  if (tid < BKN) {
    cur[tid] = nstart[tid];
    int node = node0 + tid;
    if (node < n_nodes) offsets[node] = base + nstart[tid];
  }
  if (bk == 0 && tid == 0) offsets[n_nodes] = n_edges;
  __syncthreads();

  for (int i = tid; i < tot; i += 256) {
    unsigned p = ebuf[i];
    int pos = atomicAdd(&cur[p >> 16], 1);
    sorted[(size_t)base + pos] = p;
  }
}

// ---------------------------------------------------------------------------
// Accum: wave per dst node, register accumulation, 4-deep branch-free gather
// unroll (clamped index, zero weight on tail) for latency hiding.
// ---------------------------------------------------------------------------
__global__ __launch_bounds__(256) void accum_sorted_kernel(
    const int* __restrict__ offsets, const unsigned* __restrict__ sorted,
    const float* __restrict__ explog, const unsigned* __restrict__ nbf32,
    float* __restrict__ out, int n_nodes) {
  int node = (blockIdx.x * 256 + threadIdx.x) >> 6;
  int lane = threadIdx.x & 63;
  if (node >= n_nodes) return;
  int beg = offsets[node], end = offsets[node + 1];
  float acc0 = 0.f, acc1 = 0.f, den = 0.f;
  for (int e = beg; e < end; e += 4) {
    int e1 = (e + 1 < end) ? e + 1 : end - 1;
    int e2 = (e + 2 < end) ? e + 2 : end - 1;
    int e3 = (e + 3 < end) ? e + 3 : end - 1;
    unsigned p0 = sorted[e], p1 = sorted[e1];
    unsigned p2 = sorted[e2], p3 = sorted[e3];
    int s0 = p0 & 0xFFFF, s1 = p1 & 0xFFFF;
    int s2 = p2 & 0xFFFF, s3 = p3 & 0xFFFF;
    float x0 = explog[s0];
    float x1 = (e + 1 < end) ? explog[s1] : 0.f;
    float x2 = (e + 2 < end) ? explog[s2] : 0.f;
    float x3 = (e + 3 < end) ? explog[s3] : 0.f;
    unsigned u0 = nbf32[(size_t)s0 * 64 + lane];
    unsigned u1 = nbf32[(size_t)s1 * 64 + lane];
    unsigned u2 = nbf32[(size_t)s2 * 64 + lane];
    unsigned u3 = nbf32[(size_t)s3 * 64 + lane];
    den += (x0 + x1) + (x2 + x3);
    acc0 += x0 * __uint_as_float(u0 << 16) + x1 * __uint_as_float(u1 << 16) +
            x2 * __uint_as_float(u2 << 16) + x3 * __uint_as_float(u3 << 16);
    acc1 += x0 * __uint_as_float(u0 & 0xFFFF0000u) +
            x1 * __uint_as_float(u1 & 0xFFFF0000u) +
            x2 * __uint_as_float(u2 & 0xFFFF0000u) +
            x3 * __uint_as_float(u3 & 0xFFFF0000u);
  }
  float inv = (end > beg) ? 1.0f / den : 0.f;
  *(float2*)(out + (size_t)node * D + lane * 2) =
      make_float2(acc0 * inv, acc1 * inv);
}

// ---------------------------------------------------------------------------
// Fallback path: scalar logit + per-edge atomics (R1, verified)
// ---------------------------------------------------------------------------
__global__ __launch_bounds__(256) void logit_kernel(
    const float* __restrict__ Nm, const float* __restrict__ W1,
    const float* __restrict__ w2, float* __restrict__ logit, int n_nodes) {
  __shared__ float w1t[32 * 129];
  const int tid = threadIdx.x;
  const int j = tid & 127;
  const int half = tid >> 7;
  const int base = blockIdx.x * NPB;
  float acc[8];
#pragma unroll
  for (int g = 0; g < 8; ++g) acc[g] = 0.f;
  for (int c = 0; c < 4; ++c) {
    __syncthreads();
    for (int idx = tid; idx < 128 * 32; idx += 256) {
      int kl = idx & 31, jj = idx >> 5;
      w1t[kl * 129 + jj] = W1[jj * 128 + c * 32 + kl];
    }
    __syncthreads();
#pragma unroll
    for (int g = 0; g < 8; ++g) {
      int node = base + g * 2 + half;
      if (node < n_nodes) {
        const float4* nrow =
            reinterpret_cast<const float4*>(Nm + (size_t)node * D + c * 32);
        float a = acc[g];
#pragma unroll
        for (int k4 = 0; k4 < 8; ++k4) {
          float4 nv = nrow[k4];
          int kl = k4 * 4;
          a += nv.x * w1t[(kl + 0) * 129 + j];
          a += nv.y * w1t[(kl + 1) * 129 + j];
          a += nv.z * w1t[(kl + 2) * 129 + j];
          a += nv.w * w1t[(kl + 3) * 129 + j];
        }
        acc[g] = a;
      }
    }
  }
  const float w2j = w2[j];
#pragma unroll
  for (int g = 0; g < 8; ++g) {
    int node = base + g * 2 + half;
    float t = tanhf(acc[g]) * w2j;
#pragma unroll
    for (int off = 32; off; off >>= 1) t += __shfl_down(t, off);
    if ((tid & 63) == 0 && node < n_nodes) atomicAdd(&logit[node], t);
  }
}

__global__ __launch_bounds__(256) void denom_kernel(
    const int* __restrict__ src, const int* __restrict__ dst,
    const float* __restrict__ logit, float* __restrict__ denom, int n_edges) {
  int e = blockIdx.x * 256 + threadIdx.x;
  if (e < n_edges) {
    float ex = expf(logit[src[e]]);
    atomicAdd(&denom[dst[e]], ex);
  }
}

__global__ __launch_bounds__(256) void scatter_kernel(
    const int* __restrict__ src, const int* __restrict__ dst,
    const float* __restrict__ logit, const float* __restrict__ denom,
    const float* __restrict__ Nm, float* __restrict__ out, int n_edges) {
  int wave = (blockIdx.x * 256 + threadIdx.x) >> 6;
  int lane = threadIdx.x & 63;
  if (wave >= n_edges) return;
  int s = src[wave];
  int d = dst[wave];
  float a = expf(logit[s]) / denom[d];
  float v0 = Nm[(size_t)s * D + lane];
  float v1 = Nm[(size_t)s * D + 64 + lane];
  atomicAdd(&out[(size_t)d * D + lane], a * v0);
  atomicAdd(&out[(size_t)d * D + 64 + lane], a * v1);
}

static inline char* align_up(char* p, size_t a) {
  return (char*)(((uintptr_t)p + a - 1) & ~(uintptr_t)(a - 1));
}

extern "C" void kernel_launch(void* const* d_in, const int* in_sizes, int n_in,
                              void* d_out, int out_size, void* d_ws,
                              size_t ws_size, hipStream_t stream) {
  const float* Nm  = (const float*)d_in[0];
  const float* W1  = (const float*)d_in[1];
  const float* w2  = (const float*)d_in[2];
  const int*   src = (const int*)d_in[3];
  const int*   dst = (const int*)d_in[4];
  float* out = (float*)d_out;

  const int n_nodes = in_sizes[0] / D;
  const int n_edges = in_sizes[3];
  const int n_pad = (n_nodes + 63) & ~63;
  const int nbuck = (n_nodes + BKN - 1) / BKN;
  const int nblk_bin = (n_edges + CHUNK - 1) / CHUNK;

  // carve workspace
  char* p = (char*)d_ws;
  float* logit  = (float*)p;     p = align_up(p + (size_t)n_pad * 4, 256);
  float* explog = (float*)p;     p = align_up(p + (size_t)n_pad * 4, 256);
  unsigned short* w1hi = (unsigned short*)p; p = align_up(p + 128 * 128 * 2, 256);
  unsigned short* w1lo = (unsigned short*)p; p = align_up(p + 128 * 128 * 2, 256);
  unsigned short* nbf = (unsigned short*)p;
  p = align_up(p + (size_t)n_nodes * D * 2, 256);
  unsigned* binout = (unsigned*)p;
  p = align_up(p + (size_t)nblk_bin * CHUNK * 4, 256);
  unsigned short* dir = (unsigned short*)p;
  p = align_up(p + (size_t)nblk_bin * (nbuck + 1) * 2, 256);
  unsigned* sorted = (unsigned*)p;
  p = align_up(p + (size_t)n_edges * 4, 256);
  int* offsets = (int*)p;        p = align_up(p + (size_t)(n_nodes + 1) * 4, 256);
  int* blen    = (int*)p;        p = align_up(p + (size_t)nbuck * 4, 256);
  int* bbase   = (int*)p;        p = align_up(p + (size_t)nbuck * 4, 256);
  size_t needed = (size_t)(p - (char*)d_ws);

  hipMemsetAsync(logit, 0, (size_t)n_pad * sizeof(float), stream);

  const bool fits = (ws_size >= needed) && (n_nodes <= 65535) &&
                    (nbuck <= MAXBUCK) && (nblk_bin <= NCHUNK_MAX) &&
                    ((n_edges / (nbuck > 0 ? nbuck : 1)) * 3 < CAP);

  if (fits) {
    // logit chain (also exports nbf)
    w1_convert_kernel<<<64, 256, 0, stream>>>(W1, w1hi, w1lo);
    int nblk1 = (n_nodes + 63) / 64;
    logit_mfma_kernel<<<nblk1, 256, 0, stream>>>(Nm, w1hi, w1lo, w2, logit,
                                                 nbf, n_nodes);
    int nblkE = (n_nodes + 255) / 256;
    exp_kernel<<<nblkE, 256, 0, stream>>>(logit, explog, n_nodes);

    // edge sort: chunk-local bin -> bucket bases -> per-bucket merge
    bin_kernel<<<nblk_bin, 256, 0, stream>>>(src, dst, binout, dir, n_edges,
                                             nbuck);
    btot_kernel<<<(nbuck + 255) / 256, 256, 0, stream>>>(dir, blen, nbuck,
                                                         nblk_bin);
    bscan_kernel<<<1, 1024, 0, stream>>>(blen, bbase, nbuck);
    merge_kernel<<<nbuck, 256, 0, stream>>>(binout, dir, bbase, sorted,
                                            offsets, n_nodes, nbuck, nblk_bin,
                                            n_edges);

    // accumulation (wave per node, registers only)
    int ablk = (n_nodes + 3) / 4;
    accum_sorted_kernel<<<ablk, 256, 0, stream>>>(
        offsets, sorted, explog, (const unsigned*)nbf, out, n_nodes);
  } else {
    // fallback: scalar logit + R1 atomic path
    int nblk1 = (n_nodes + NPB - 1) / NPB;
    logit_kernel<<<nblk1, 256, 0, stream>>>(Nm, W1, w2, logit, n_nodes);
    float* denom = logit + n_pad;
    hipMemsetAsync(denom, 0, (size_t)n_pad * sizeof(float), stream);
    hipMemsetAsync(out, 0, (size_t)out_size * sizeof(float), stream);
    int eblk = (n_edges + 255) / 256;
    denom_kernel<<<eblk, 256, 0, stream>>>(src, dst, logit, denom, n_edges);
    int nblk3 = (n_edges + 3) / 4;
    scatter_kernel<<<nblk3, 256, 0, stream>>>(src, dst, logit, denom, Nm, out,
                                              n_edges);
  }
}

// Round 7
// 118.788 us; speedup vs baseline: 6.3938x; 1.0959x over previous
//
#include <hip/hip_runtime.h>
#include <hip/hip_bf16.h>

#define D 128
#define NPB 16           // nodes per block in fallback logit kernel
#define CHUNK 8192       // edges per bin block
#define BKN 64           // dst nodes per bucket
#define MAXBUCK 1024     // max buckets
#define NCHUNK_MAX 128   // max bin chunks supported by merge
#define CAP 4096         // per-bucket window & merge LDS buffer (avg ~1024)

typedef __attribute__((ext_vector_type(8))) short bf16x8;
typedef __attribute__((ext_vector_type(4))) float f32x4;

__device__ __forceinline__ unsigned short f2bf_rne(float f) {
  unsigned u = __float_as_uint(f);
  unsigned r = (u + 0x7FFFu + ((u >> 16) & 1u)) >> 16;
  return (unsigned short)r;
}

__device__ __forceinline__ float fast_tanh(float x) {
  float e = __expf(2.0f * x);
  return 1.0f - 2.0f / (e + 1.0f);
}

// ---------------------------------------------------------------------------
// W1 -> bf16 hi/lo split
// ---------------------------------------------------------------------------
__global__ __launch_bounds__(256) void w1_convert_kernel(
    const float* __restrict__ W1, unsigned short* __restrict__ w1hi,
    unsigned short* __restrict__ w1lo) {
  int i = blockIdx.x * 256 + threadIdx.x;
  float x = W1[i];
  unsigned short h = f2bf_rne(x);
  float hf = __uint_as_float((unsigned)h << 16);
  w1hi[i] = h;
  w1lo[i] = f2bf_rne(x - hf);
}

// ---------------------------------------------------------------------------
// logit chain fused: split-bf16 MFMA (R3-verified), nbf export, cross-wave
// LDS reduction of the 4 per-wave j-partials, exp -> explog. No atomics.
// ---------------------------------------------------------------------------
__global__ __launch_bounds__(256, 2) void logit_mfma_kernel(
    const float* __restrict__ Nm, const unsigned short* __restrict__ w1hi,
    const unsigned short* __restrict__ w1lo, const float* __restrict__ w2,
    float* __restrict__ explog, unsigned short* __restrict__ nbf,
    int n_nodes) {
  __shared__ unsigned short lhi[64 * 128];
  __shared__ unsigned short llo[64 * 128];
  __shared__ float part[4][64];
  const int tid = threadIdx.x;
  const int w = tid >> 6;
  const int l = tid & 63;
  const int lg = l >> 4;
  const int ln = l & 15;
  const int base = blockIdx.x * 64;

  bf16x8 Bh[2][4], Bl[2][4];
#pragma unroll
  for (int ntl = 0; ntl < 2; ++ntl) {
    int n = (w * 2 + ntl) * 16 + ln;
#pragma unroll
    for (int kt = 0; kt < 4; ++kt) {
      int k = kt * 32 + lg * 8;
      Bh[ntl][kt] = *(const bf16x8*)(w1hi + n * 128 + k);
      Bl[ntl][kt] = *(const bf16x8*)(w1lo + n * 128 + k);
    }
  }

#pragma unroll
  for (int i = 0; i < 8; ++i) {
    int flat = tid + i * 256;
    int row = flat >> 5;
    int c4 = flat & 31;
    int grow = base + row;
    if (grow >= n_nodes) grow = n_nodes - 1;
    float4 v = *(const float4*)(Nm + (size_t)grow * D + c4 * 4);
    unsigned short h0 = f2bf_rne(v.x), h1 = f2bf_rne(v.y);
    unsigned short h2 = f2bf_rne(v.z), h3 = f2bf_rne(v.w);
    unsigned short o0 = f2bf_rne(v.x - __uint_as_float((unsigned)h0 << 16));
    unsigned short o1 = f2bf_rne(v.y - __uint_as_float((unsigned)h1 << 16));
    unsigned short o2 = f2bf_rne(v.z - __uint_as_float((unsigned)h2 << 16));
    unsigned short o3 = f2bf_rne(v.w - __uint_as_float((unsigned)h3 << 16));
    int boff = (c4 * 8) ^ ((row & 7) << 4);
    *(ushort4*)((char*)lhi + row * 256 + boff) = make_ushort4(h0, h1, h2, h3);
    *(ushort4*)((char*)llo + row * 256 + boff) = make_ushort4(o0, o1, o2, o3);
    *(ushort4*)(nbf + (size_t)grow * D + c4 * 4) =
        make_ushort4(h0, h1, h2, h3);
  }
  __syncthreads();

  f32x4 acc[4][2];
#pragma unroll
  for (int mt = 0; mt < 4; ++mt)
#pragma unroll
    for (int ntl = 0; ntl < 2; ++ntl) acc[mt][ntl] = (f32x4){0.f, 0.f, 0.f, 0.f};

#pragma unroll
  for (int mt = 0; mt < 4; ++mt) {
    int row = mt * 16 + ln;
    bf16x8 Ah[4], Al[4];
#pragma unroll
    for (int kt = 0; kt < 4; ++kt) {
      int boff = (kt * 64 + lg * 16) ^ ((row & 7) << 4);
      Ah[kt] = *(const bf16x8*)((const char*)lhi + row * 256 + boff);
      Al[kt] = *(const bf16x8*)((const char*)llo + row * 256 + boff);
    }
#pragma unroll
    for (int ntl = 0; ntl < 2; ++ntl) {
#pragma unroll
      for (int kt = 0; kt < 4; ++kt) {
        acc[mt][ntl] = __builtin_amdgcn_mfma_f32_16x16x32_bf16(
            Ah[kt], Bh[ntl][kt], acc[mt][ntl], 0, 0, 0);
        acc[mt][ntl] = __builtin_amdgcn_mfma_f32_16x16x32_bf16(
            Ah[kt], Bl[ntl][kt], acc[mt][ntl], 0, 0, 0);
        acc[mt][ntl] = __builtin_amdgcn_mfma_f32_16x16x32_bf16(
            Al[kt], Bh[ntl][kt], acc[mt][ntl], 0, 0, 0);
      }
    }
  }

  float w2a = w2[(w * 2 + 0) * 16 + ln];
  float w2b = w2[(w * 2 + 1) * 16 + ln];
#pragma unroll
  for (int mt = 0; mt < 4; ++mt) {
    float s0 = fast_tanh(acc[mt][0][0]) * w2a + fast_tanh(acc[mt][1][0]) * w2b;
    float s1 = fast_tanh(acc[mt][0][1]) * w2a + fast_tanh(acc[mt][1][1]) * w2b;
    float s2 = fast_tanh(acc[mt][0][2]) * w2a + fast_tanh(acc[mt][1][2]) * w2b;
    float s3 = fast_tanh(acc[mt][0][3]) * w2a + fast_tanh(acc[mt][1][3]) * w2b;
#pragma unroll
    for (int mask = 1; mask < 16; mask <<= 1) {
      s0 += __shfl_xor(s0, mask);
      s1 += __shfl_xor(s1, mask);
      s2 += __shfl_xor(s2, mask);
      s3 += __shfl_xor(s3, mask);
    }
    if (ln < 4) {
      float sv = (ln == 0) ? s0 : (ln == 1) ? s1 : (ln == 2) ? s2 : s3;
      part[w][mt * 16 + lg * 4 + ln] = sv;
    }
  }
  __syncthreads();
  if (tid < 64) {
    int node = base + tid;
    if (node < n_nodes) {
      float t = part[0][tid] + part[1][tid] + part[2][tid] + part[3][tid];
      explog[node] = expf(t);
    }
  }
}

// ---------------------------------------------------------------------------
// Bin: chunk-local LDS counting sort by bucket (dst>>6); coalesced output.
// binout entry = src | (dst&63)<<16 ; dir[blk][k] = run start (u16).
// ---------------------------------------------------------------------------
__global__ __launch_bounds__(256) void bin_kernel(
    const int* __restrict__ src, const int* __restrict__ dst,
    unsigned* __restrict__ binout, unsigned short* __restrict__ dir,
    int n_edges, int nbuck) {
  __shared__ unsigned cnt[MAXBUCK];
  __shared__ unsigned cur[MAXBUCK];
  __shared__ unsigned ebuf[CHUNK];
  __shared__ int sdata[256];
  const int tid = threadIdx.x;
  const int blk = blockIdx.x;
  const int ebase = blk * CHUNK;
  const int chunkN = min(CHUNK, n_edges - ebase);

  for (int i = tid; i < MAXBUCK; i += 256) cnt[i] = 0;
  __syncthreads();

  for (int i = tid; i < chunkN; i += 256) {
    int d = dst[ebase + i];
    atomicAdd(&cnt[d >> 6], 1u);
  }
  __syncthreads();

  int t4 = tid * 4;
  int c0 = cnt[t4], c1 = cnt[t4 + 1], c2 = cnt[t4 + 2], c3 = cnt[t4 + 3];
  int s = c0 + c1 + c2 + c3;
  sdata[tid] = s;
  __syncthreads();
  for (int d = 1; d < 256; d <<= 1) {
    int v = (tid >= d) ? sdata[tid - d] : 0;
    __syncthreads();
    sdata[tid] += v;
    __syncthreads();
  }
  int tb = sdata[tid] - s;
  cur[t4] = tb;
  cur[t4 + 1] = tb + c0;
  cur[t4 + 2] = tb + c0 + c1;
  cur[t4 + 3] = tb + c0 + c1 + c2;
  __syncthreads();

  size_t dbase = (size_t)blk * (nbuck + 1);
  for (int k = tid; k < nbuck; k += 256) dir[dbase + k] = (unsigned short)cur[k];
  if (tid == 0) dir[dbase + nbuck] = (unsigned short)chunkN;
  __syncthreads();

  for (int i = tid; i < chunkN; i += 256) {
    int d = dst[ebase + i];
    int sv = src[ebase + i];
    unsigned slot = atomicAdd(&cur[d >> 6], 1u);
    ebuf[slot] = (unsigned)sv | ((unsigned)(d & 63) << 16);
  }
  __syncthreads();

  for (int i = tid; i < chunkN; i += 256) binout[ebase + i] = ebuf[i];
}

// ---------------------------------------------------------------------------
// Merge: one block per bucket -> private fixed window sorted[bk*CAP ...].
// Gathers this bucket's runs, 64-counter counting sort, writes dst-sorted
// edges + per-node [offsets, ends]. No global scan needed.
// ---------------------------------------------------------------------------
__global__ __launch_bounds__(256) void merge_kernel(
    const unsigned* __restrict__ binout, const unsigned short* __restrict__ dir,
    unsigned* __restrict__ sorted, int* __restrict__ offsets,
    int* __restrict__ ends, int n_nodes, int nbuck, int nblk_bin) {
  __shared__ unsigned ebuf[CAP];
  __shared__ int lens[NCHUNK_MAX], cstart[NCHUNK_MAX], ls0[NCHUNK_MAX];
  __shared__ int cnt[BKN], nstart[BKN], cur[BKN];
  __shared__ int total;
  const int tid = threadIdx.x;
  const int w = tid >> 6, lane = tid & 63;
  const int bk = blockIdx.x;
  const int node0 = bk * BKN;
  const int base = bk * CAP;

  if (tid < nblk_bin) {
    size_t dbase = (size_t)tid * (nbuck + 1);
    int s0 = dir[dbase + bk];
    int s1 = dir[dbase + bk + 1];
    ls0[tid] = s0;
    lens[tid] = s1 - s0;
  }
  if (tid < BKN) cnt[tid] = 0;
  __syncthreads();
  if (tid == 0) {
    int run = 0;
    for (int r = 0; r < nblk_bin; ++r) {
      cstart[r] = run;
      run += lens[r];
    }
    total = (run > CAP) ? CAP : run;
  }
  __syncthreads();
  const int tot = total;

  for (int r = w; r < nblk_bin; r += 4) {
    int len = lens[r], cs = cstart[r];
    if (cs >= CAP) continue;
    if (cs + len > CAP) len = CAP - cs;
    const unsigned* g = binout + (size_t)r * CHUNK + ls0[r];
    for (int i = lane; i < len; i += 64) ebuf[cs + i] = g[i];
  }
  __syncthreads();

  for (int i = tid; i < tot; i += 256) atomicAdd(&cnt[ebuf[i] >> 16], 1);
  __syncthreads();
  if (tid == 0) {
    int run = 0;
    for (int t = 0; t < BKN; ++t) {
      nstart[t] = run;
      run += cnt[t];
    }
  }
  __syncthreads();

  if (tid < BKN) {
    cur[tid] = nstart[tid];
    int node = node0 + tid;
    if (node < n_nodes) {
      offsets[node] = base + nstart[tid];
      ends[node] = base + nstart[tid] + cnt[tid];
    }
  }
  __syncthreads();

  for (int i = tid; i < tot; i += 256) {
    unsigned p = ebuf[i];
    int pos = atomicAdd(&cur[p >> 16], 1);
    sorted[(size_t)base + pos] = p;
  }
}

// ---------------------------------------------------------------------------
// Accum: wave per dst node. Wave-uniform data (offsets/ends/sorted/explog)
// scalarized via readfirstlane -> s_loads on the scalar pipe; only nbf
// gathers use vmem. 8-deep unroll for latency hiding.
// ---------------------------------------------------------------------------
__global__ __launch_bounds__(256) void accum_sorted_kernel(
    const int* __restrict__ offsets, const int* __restrict__ ends,
    const unsigned* __restrict__ sorted, const float* __restrict__ explog,
    const unsigned* __restrict__ nbf32, float* __restrict__ out, int n_nodes) {
  int node = (blockIdx.x * 256 + threadIdx.x) >> 6;
  int lane = threadIdx.x & 63;
  if (node >= n_nodes) return;
  node = __builtin_amdgcn_readfirstlane(node);
  int beg = offsets[node];
  int end = ends[node];
  float acc0 = 0.f, acc1 = 0.f, den = 0.f;
  for (int e = beg; e < end; e += 8) {
    int last = end - 1;
    unsigned p[8];
    float x[8];
    unsigned u[8];
#pragma unroll
    for (int i = 0; i < 8; ++i) {
      int ei = e + i;
      int ec = (ei < last) ? ei : last;
      p[i] = sorted[ec];
    }
#pragma unroll
    for (int i = 0; i < 8; ++i) {
      int si = p[i] & 0xFFFF;
      x[i] = (e + i < end) ? explog[si] : 0.f;
      u[i] = nbf32[(size_t)si * 64 + lane];
    }
#pragma unroll
    for (int i = 0; i < 8; ++i) {
      den += x[i];
      acc0 += x[i] * __uint_as_float(u[i] << 16);
      acc1 += x[i] * __uint_as_float(u[i] & 0xFFFF0000u);
    }
  }
  float inv = (end > beg) ? 1.0f / den : 0.f;
  *(float2*)(out + (size_t)node * D + lane * 2) =
      make_float2(acc0 * inv, acc1 * inv);
}

// ---------------------------------------------------------------------------
// Fallback path: scalar logit + per-edge atomics (R1, verified)
// ---------------------------------------------------------------------------
__global__ __launch_bounds__(256) void logit_kernel(
    const float* __restrict__ Nm, const float* __restrict__ W1,
    const float* __restrict__ w2, float* __restrict__ logit, int n_nodes) {
  __shared__ float w1t[32 * 129];
  const int tid = threadIdx.x;
  const int j = tid & 127;
  const int half = tid >> 7;
  const int base = blockIdx.x * NPB;
  float acc[8];
#pragma unroll
  for (int g = 0; g < 8; ++g) acc[g] = 0.f;
  for (int c = 0; c < 4; ++c) {
    __syncthreads();
    for (int idx = tid; idx < 128 * 32; idx += 256) {
      int kl = idx & 31, jj = idx >> 5;
      w1t[kl * 129 + jj] = W1[jj * 128 + c * 32 + kl];
    }
    __syncthreads();
#pragma unroll
    for (int g = 0; g < 8; ++g) {
      int node = base + g * 2 + half;
      if (node < n_nodes) {
        const float4* nrow =
            reinterpret_cast<const float4*>(Nm + (size_t)node * D + c * 32);
        float a = acc[g];
#pragma unroll
        for (int k4 = 0; k4 < 8; ++k4) {
          float4 nv = nrow[k4];
          int kl = k4 * 4;
          a += nv.x * w1t[(kl + 0) * 129 + j];
          a += nv.y * w1t[(kl + 1) * 129 + j];
          a += nv.z * w1t[(kl + 2) * 129 + j];
          a += nv.w * w1t[(kl + 3) * 129 + j];
        }
        acc[g] = a;
      }
    }
  }
  const float w2j = w2[j];
#pragma unroll
  for (int g = 0; g < 8; ++g) {
    int node = base + g * 2 + half;
    float t = tanhf(acc[g]) * w2j;
#pragma unroll
    for (int off = 32; off; off >>= 1) t += __shfl_down(t, off);
    if ((tid & 63) == 0 && node < n_nodes) atomicAdd(&logit[node], t);
  }
}

__global__ __launch_bounds__(256) void denom_kernel(
    const int* __restrict__ src, const int* __restrict__ dst,
    const float* __restrict__ logit, float* __restrict__ denom, int n_edges) {
  int e = blockIdx.x * 256 + threadIdx.x;
  if (e < n_edges) {
    float ex = expf(logit[src[e]]);
    atomicAdd(&denom[dst[e]], ex);
  }
}

__global__ __launch_bounds__(256) void scatter_kernel(
    const int* __restrict__ src, const int* __restrict__ dst,
    const float* __restrict__ logit, const float* __restrict__ denom,
    const float* __restrict__ Nm, float* __restrict__ out, int n_edges) {
  int wave = (blockIdx.x * 256 + threadIdx.x) >> 6;
  int lane = threadIdx.x & 63;
  if (wave >= n_edges) return;
  int s = src[wave];
  int d = dst[wave];
  float a = expf(logit[s]) / denom[d];
  float v0 = Nm[(size_t)s * D + lane];
  float v1 = Nm[(size_t)s * D + 64 + lane];
  atomicAdd(&out[(size_t)d * D + lane], a * v0);
  atomicAdd(&out[(size_t)d * D + 64 + lane], a * v1);
}

static inline char* align_up(char* p, size_t a) {
  return (char*)(((uintptr_t)p + a - 1) & ~(uintptr_t)(a - 1));
}

extern "C" void kernel_launch(void* const* d_in, const int* in_sizes, int n_in,
                              void* d_out, int out_size, void* d_ws,
                              size_t ws_size, hipStream_t stream) {
  const float* Nm  = (const float*)d_in[0];
  const float* W1  = (const float*)d_in[1];
  const float* w2  = (const float*)d_in[2];
  const int*   src = (const int*)d_in[3];
  const int*   dst = (const int*)d_in[4];
  float* out = (float*)d_out;

  const int n_nodes = in_sizes[0] / D;
  const int n_edges = in_sizes[3];
  const int n_pad = (n_nodes + 63) & ~63;
  const int nbuck = (n_nodes + BKN - 1) / BKN;
  const int nblk_bin = (n_edges + CHUNK - 1) / CHUNK;

  // carve workspace
  char* p = (char*)d_ws;
  float* explog = (float*)p;     p = align_up(p + (size_t)n_pad * 4, 256);
  float* denomF = (float*)p;     p = align_up(p + (size_t)n_pad * 4, 256);
  unsigned short* w1hi = (unsigned short*)p; p = align_up(p + 128 * 128 * 2, 256);
  unsigned short* w1lo = (unsigned short*)p; p = align_up(p + 128 * 128 * 2, 256);
  unsigned short* nbf = (unsigned short*)p;
  p = align_up(p + (size_t)n_nodes * D * 2, 256);
  unsigned* binout = (unsigned*)p;
  p = align_up(p + (size_t)nblk_bin * CHUNK * 4, 256);
  unsigned short* dir = (unsigned short*)p;
  p = align_up(p + (size_t)nblk_bin * (nbuck + 1) * 2, 256);
  unsigned* sorted = (unsigned*)p;
  p = align_up(p + (size_t)nbuck * CAP * 4, 256);
  int* offsets = (int*)p;        p = align_up(p + (size_t)n_pad * 4, 256);
  int* ends    = (int*)p;        p = align_up(p + (size_t)n_pad * 4, 256);
  size_t needed = (size_t)(p - (char*)d_ws);

  const bool fits = (ws_size >= needed) && (n_nodes <= 65535) &&
                    (nbuck <= MAXBUCK) && (nblk_bin <= NCHUNK_MAX) &&
                    ((n_edges / (nbuck > 0 ? nbuck : 1)) * 3 < CAP);

  if (fits) {
    // logit chain (fused: logits + exp + nbf export, no atomics/memset)
    w1_convert_kernel<<<64, 256, 0, stream>>>(W1, w1hi, w1lo);
    int nblk1 = (n_nodes + 63) / 64;
    logit_mfma_kernel<<<nblk1, 256, 0, stream>>>(Nm, w1hi, w1lo, w2, explog,
                                                 nbf, n_nodes);

    // edge sort: chunk-local bin -> per-bucket merge (private windows)
    bin_kernel<<<nblk_bin, 256, 0, stream>>>(src, dst, binout, dir, n_edges,
                                             nbuck);
    merge_kernel<<<nbuck, 256, 0, stream>>>(binout, dir, sorted, offsets,
                                            ends, n_nodes, nbuck, nblk_bin);

    // accumulation (wave per node, scalarized uniform loads)
    int ablk = (n_nodes + 3) / 4;
    accum_sorted_kernel<<<ablk, 256, 0, stream>>>(
        offsets, ends, sorted, explog, (const unsigned*)nbf, out, n_nodes);
  } else {
    // fallback: scalar logit + R1 atomic path
    float* logit = explog;
    float* denom = denomF;
    hipMemsetAsync(logit, 0, (size_t)n_pad * sizeof(float), stream);
    hipMemsetAsync(denom, 0, (size_t)n_pad * sizeof(float), stream);
    hipMemsetAsync(out, 0, (size_t)out_size * sizeof(float), stream);
    int nblk1 = (n_nodes + NPB - 1) / NPB;
    logit_kernel<<<nblk1, 256, 0, stream>>>(Nm, W1, w2, logit, n_nodes);
    int eblk = (n_edges + 255) / 256;
    denom_kernel<<<eblk, 256, 0, stream>>>(src, dst, logit, denom, n_edges);
    int nblk3 = (n_edges + 3) / 4;
    scatter_kernel<<<nblk3, 256, 0, stream>>>(src, dst, logit, denom, Nm, out,
                                              n_edges);
  }
}

// Round 8
// 95.221 us; speedup vs baseline: 7.9763x; 1.2475x over previous
//
#include <hip/hip_runtime.h>
#include <hip/hip_bf16.h>

#define D 128
#define NPB 16           // nodes per block in fallback logit kernel
#define CHUNK 8192       // edges per bin block
#define BKN 64           // dst nodes per bucket
#define MAXBUCK 1024     // max buckets
#define NCHUNK_MAX 128   // max bin chunks supported by merge
#define CAP 4096         // per-bucket window & merge LDS buffer (avg ~1024)

typedef __attribute__((ext_vector_type(8))) short bf16x8;
typedef __attribute__((ext_vector_type(4))) float f32x4;

__device__ __forceinline__ unsigned short f2bf_rne(float f) {
  unsigned u = __float_as_uint(f);
  unsigned r = (u + 0x7FFFu + ((u >> 16) & 1u)) >> 16;
  return (unsigned short)r;
}

__device__ __forceinline__ float fast_tanh(float x) {
  float e = __expf(2.0f * x);
  return 1.0f - 2.0f / (e + 1.0f);
}

// split 8 consecutive f32 into bf16 hi/lo fragments (in registers)
__device__ __forceinline__ void split8(const float* __restrict__ p,
                                       bf16x8& hv, bf16x8& lv) {
  float4 a = *(const float4*)p;
  float4 b = *(const float4*)(p + 4);
  float xs[8] = {a.x, a.y, a.z, a.w, b.x, b.y, b.z, b.w};
#pragma unroll
  for (int i = 0; i < 8; ++i) {
    unsigned short h = f2bf_rne(xs[i]);
    float hf = __uint_as_float((unsigned)h << 16);
    hv[i] = (short)h;
    lv[i] = (short)f2bf_rne(xs[i] - hf);
  }
}

// ---------------------------------------------------------------------------
// logit chain fused: in-register W1 f32->bf16 hi/lo split, split-bf16 MFMA
// (R3-verified mapping), nbf export, cross-wave LDS reduction, exp -> explog.
// ---------------------------------------------------------------------------
__global__ __launch_bounds__(256, 2) void logit_mfma_kernel(
    const float* __restrict__ Nm, const float* __restrict__ W1,
    const float* __restrict__ w2, float* __restrict__ explog,
    unsigned short* __restrict__ nbf, int n_nodes) {
  __shared__ unsigned short lhi[64 * 128];
  __shared__ unsigned short llo[64 * 128];
  __shared__ float part[4][64];
  const int tid = threadIdx.x;
  const int w = tid >> 6;
  const int l = tid & 63;
  const int lg = l >> 4;
  const int ln = l & 15;
  const int base = blockIdx.x * 64;

  // ---- B fragments: load W1 f32 rows, split to bf16 hi/lo in registers ----
  bf16x8 Bh[2][4], Bl[2][4];
#pragma unroll
  for (int ntl = 0; ntl < 2; ++ntl) {
    int n = (w * 2 + ntl) * 16 + ln;  // W1 row = output feature j
#pragma unroll
    for (int kt = 0; kt < 4; ++kt) {
      int k = kt * 32 + lg * 8;
      split8(W1 + n * 128 + k, Bh[ntl][kt], Bl[ntl][kt]);
    }
  }

  // ---- stage A: 64 rows of N -> bf16 hi/lo swizzled LDS + nbf export ----
#pragma unroll
  for (int i = 0; i < 8; ++i) {
    int flat = tid + i * 256;
    int row = flat >> 5;
    int c4 = flat & 31;
    int grow = base + row;
    if (grow >= n_nodes) grow = n_nodes - 1;
    float4 v = *(const float4*)(Nm + (size_t)grow * D + c4 * 4);
    unsigned short h0 = f2bf_rne(v.x), h1 = f2bf_rne(v.y);
    unsigned short h2 = f2bf_rne(v.z), h3 = f2bf_rne(v.w);
    unsigned short o0 = f2bf_rne(v.x - __uint_as_float((unsigned)h0 << 16));
    unsigned short o1 = f2bf_rne(v.y - __uint_as_float((unsigned)h1 << 16));
    unsigned short o2 = f2bf_rne(v.z - __uint_as_float((unsigned)h2 << 16));
    unsigned short o3 = f2bf_rne(v.w - __uint_as_float((unsigned)h3 << 16));
    int boff = (c4 * 8) ^ ((row & 7) << 4);
    *(ushort4*)((char*)lhi + row * 256 + boff) = make_ushort4(h0, h1, h2, h3);
    *(ushort4*)((char*)llo + row * 256 + boff) = make_ushort4(o0, o1, o2, o3);
    *(ushort4*)(nbf + (size_t)grow * D + c4 * 4) =
        make_ushort4(h0, h1, h2, h3);
  }
  __syncthreads();

  // ---- MFMA main ----
  f32x4 acc[4][2];
#pragma unroll
  for (int mt = 0; mt < 4; ++mt)
#pragma unroll
    for (int ntl = 0; ntl < 2; ++ntl) acc[mt][ntl] = (f32x4){0.f, 0.f, 0.f, 0.f};

#pragma unroll
  for (int mt = 0; mt < 4; ++mt) {
    int row = mt * 16 + ln;
    bf16x8 Ah[4], Al[4];
#pragma unroll
    for (int kt = 0; kt < 4; ++kt) {
      int boff = (kt * 64 + lg * 16) ^ ((row & 7) << 4);
      Ah[kt] = *(const bf16x8*)((const char*)lhi + row * 256 + boff);
      Al[kt] = *(const bf16x8*)((const char*)llo + row * 256 + boff);
    }
#pragma unroll
    for (int ntl = 0; ntl < 2; ++ntl) {
#pragma unroll
      for (int kt = 0; kt < 4; ++kt) {
        acc[mt][ntl] = __builtin_amdgcn_mfma_f32_16x16x32_bf16(
            Ah[kt], Bh[ntl][kt], acc[mt][ntl], 0, 0, 0);
        acc[mt][ntl] = __builtin_amdgcn_mfma_f32_16x16x32_bf16(
            Ah[kt], Bl[ntl][kt], acc[mt][ntl], 0, 0, 0);
        acc[mt][ntl] = __builtin_amdgcn_mfma_f32_16x16x32_bf16(
            Al[kt], Bh[ntl][kt], acc[mt][ntl], 0, 0, 0);
      }
    }
  }

  // ---- epilogue: tanh*w2, 16-lane reduce, cross-wave LDS reduce, exp ----
  float w2a = w2[(w * 2 + 0) * 16 + ln];
  float w2b = w2[(w * 2 + 1) * 16 + ln];
#pragma unroll
  for (int mt = 0; mt < 4; ++mt) {
    float s0 = fast_tanh(acc[mt][0][0]) * w2a + fast_tanh(acc[mt][1][0]) * w2b;
    float s1 = fast_tanh(acc[mt][0][1]) * w2a + fast_tanh(acc[mt][1][1]) * w2b;
    float s2 = fast_tanh(acc[mt][0][2]) * w2a + fast_tanh(acc[mt][1][2]) * w2b;
    float s3 = fast_tanh(acc[mt][0][3]) * w2a + fast_tanh(acc[mt][1][3]) * w2b;
#pragma unroll
    for (int mask = 1; mask < 16; mask <<= 1) {
      s0 += __shfl_xor(s0, mask);
      s1 += __shfl_xor(s1, mask);
      s2 += __shfl_xor(s2, mask);
      s3 += __shfl_xor(s3, mask);
    }
    if (ln < 4) {
      float sv = (ln == 0) ? s0 : (ln == 1) ? s1 : (ln == 2) ? s2 : s3;
      part[w][mt * 16 + lg * 4 + ln] = sv;
    }
  }
  __syncthreads();
  if (tid < 64) {
    int node = base + tid;
    if (node < n_nodes) {
      float t = part[0][tid] + part[1][tid] + part[2][tid] + part[3][tid];
      explog[node] = expf(t);
    }
  }
}

// ---------------------------------------------------------------------------
// Bin: chunk-local LDS counting sort by bucket (dst>>6); coalesced output.
// binout entry = src | (dst&63)<<16 ; dir[blk][k] = run start (u16).
// ---------------------------------------------------------------------------
__global__ __launch_bounds__(256) void bin_kernel(
    const int* __restrict__ src, const int* __restrict__ dst,
    unsigned* __restrict__ binout, unsigned short* __restrict__ dir,
    int n_edges, int nbuck) {
  __shared__ unsigned cnt[MAXBUCK];
  __shared__ unsigned cur[MAXBUCK];
  __shared__ unsigned ebuf[CHUNK];
  __shared__ int sdata[256];
  const int tid = threadIdx.x;
  const int blk = blockIdx.x;
  const int ebase = blk * CHUNK;
  const int chunkN = min(CHUNK, n_edges - ebase);

  for (int i = tid; i < MAXBUCK; i += 256) cnt[i] = 0;
  __syncthreads();

  for (int i = tid; i < chunkN; i += 256) {
    int d = dst[ebase + i];
    atomicAdd(&cnt[d >> 6], 1u);
  }
  __syncthreads();

  int t4 = tid * 4;
  int c0 = cnt[t4], c1 = cnt[t4 + 1], c2 = cnt[t4 + 2], c3 = cnt[t4 + 3];
  int s = c0 + c1 + c2 + c3;
  sdata[tid] = s;
  __syncthreads();
  for (int d = 1; d < 256; d <<= 1) {
    int v = (tid >= d) ? sdata[tid - d] : 0;
    __syncthreads();
    sdata[tid] += v;
    __syncthreads();
  }
  int tb = sdata[tid] - s;
  cur[t4] = tb;
  cur[t4 + 1] = tb + c0;
  cur[t4 + 2] = tb + c0 + c1;
  cur[t4 + 3] = tb + c0 + c1 + c2;
  __syncthreads();

  size_t dbase = (size_t)blk * (nbuck + 1);
  for (int k = tid; k < nbuck; k += 256) dir[dbase + k] = (unsigned short)cur[k];
  if (tid == 0) dir[dbase + nbuck] = (unsigned short)chunkN;
  __syncthreads();

  for (int i = tid; i < chunkN; i += 256) {
    int d = dst[ebase + i];
    int sv = src[ebase + i];
    unsigned slot = atomicAdd(&cur[d >> 6], 1u);
    ebuf[slot] = (unsigned)sv | ((unsigned)(d & 63) << 16);
  }
  __syncthreads();

  for (int i = tid; i < chunkN; i += 256) binout[ebase + i] = ebuf[i];
}

// ---------------------------------------------------------------------------
// Merge: one block per bucket -> private fixed window sorted[bk*CAP ...].
// Gathers this bucket's runs, 64-counter counting sort, writes dst-sorted
// edges + per-node [offsets, ends].
// ---------------------------------------------------------------------------
__global__ __launch_bounds__(256) void merge_kernel(
    const unsigned* __restrict__ binout, const unsigned short* __restrict__ dir,
    unsigned* __restrict__ sorted, int* __restrict__ offsets,
    int* __restrict__ ends, int n_nodes, int nbuck, int nblk_bin) {
  __shared__ unsigned ebuf[CAP];
  __shared__ int lens[NCHUNK_MAX], cstart[NCHUNK_MAX], ls0[NCHUNK_MAX];
  __shared__ int cnt[BKN], nstart[BKN], cur[BKN];
  __shared__ int total;
  const int tid = threadIdx.x;
  const int w = tid >> 6, lane = tid & 63;
  const int bk = blockIdx.x;
  const int node0 = bk * BKN;
  const int base = bk * CAP;

  if (tid < nblk_bin) {
    size_t dbase = (size_t)tid * (nbuck + 1);
    int s0 = dir[dbase + bk];
    int s1 = dir[dbase + bk + 1];
    ls0[tid] = s0;
    lens[tid] = s1 - s0;
  }
  if (tid < BKN) cnt[tid] = 0;
  __syncthreads();
  if (tid == 0) {
    int run = 0;
    for (int r = 0; r < nblk_bin; ++r) {
      cstart[r] = run;
      run += lens[r];
    }
    total = (run > CAP) ? CAP : run;
  }
  __syncthreads();
  const int tot = total;

  for (int r = w; r < nblk_bin; r += 4) {
    int len = lens[r], cs = cstart[r];
    if (cs >= CAP) continue;
    if (cs + len > CAP) len = CAP - cs;
    const unsigned* g = binout + (size_t)r * CHUNK + ls0[r];
    for (int i = lane; i < len; i += 64) ebuf[cs + i] = g[i];
  }
  __syncthreads();

  for (int i = tid; i < tot; i += 256) atomicAdd(&cnt[ebuf[i] >> 16], 1);
  __syncthreads();
  if (tid == 0) {
    int run = 0;
    for (int t = 0; t < BKN; ++t) {
      nstart[t] = run;
      run += cnt[t];
    }
  }
  __syncthreads();

  if (tid < BKN) {
    cur[tid] = nstart[tid];
    int node = node0 + tid;
    if (node < n_nodes) {
      offsets[node] = base + nstart[tid];
      ends[node] = base + nstart[tid] + cnt[tid];
    }
  }
  __syncthreads();

  for (int i = tid; i < tot; i += 256) {
    unsigned p = ebuf[i];
    int pos = atomicAdd(&cur[p >> 16], 1);
    sorted[(size_t)base + pos] = p;
  }
}

// ---------------------------------------------------------------------------
// Accum: wave per dst node, pure-vector register accumulation, 8-deep
// branch-free unroll (clamped index, zero weight on tail) for gather MLP.
// ---------------------------------------------------------------------------
__global__ __launch_bounds__(256) void accum_sorted_kernel(
    const int* __restrict__ offsets, const int* __restrict__ ends,
    const unsigned* __restrict__ sorted, const float* __restrict__ explog,
    const unsigned* __restrict__ nbf32, float* __restrict__ out, int n_nodes) {
  int node = (blockIdx.x * 256 + threadIdx.x) >> 6;
  int lane = threadIdx.x & 63;
  if (node >= n_nodes) return;
  int beg = offsets[node], end = ends[node];
  int last = end - 1;
  float acc0 = 0.f, acc1 = 0.f, den = 0.f;
  for (int e = beg; e < end; e += 8) {
    unsigned p[8];
    float x[8];
    unsigned u[8];
#pragma unroll
    for (int i = 0; i < 8; ++i) {
      int ei = e + i;
      int ec = (ei < last) ? ei : last;
      p[i] = sorted[ec];
    }
#pragma unroll
    for (int i = 0; i < 8; ++i) {
      int si = p[i] & 0xFFFF;
      u[i] = nbf32[(size_t)si * 64 + lane];
      x[i] = explog[si];
    }
#pragma unroll
    for (int i = 0; i < 8; ++i) {
      float xi = (e + i < end) ? x[i] : 0.f;
      den += xi;
      acc0 += xi * __uint_as_float(u[i] << 16);
      acc1 += xi * __uint_as_float(u[i] & 0xFFFF0000u);
    }
  }
  float inv = (end > beg) ? 1.0f / den : 0.f;
  *(float2*)(out + (size_t)node * D + lane * 2) =
      make_float2(acc0 * inv, acc1 * inv);
}

// ---------------------------------------------------------------------------
// Fallback path: scalar logit + per-edge atomics (R1, verified)
// ---------------------------------------------------------------------------
__global__ __launch_bounds__(256) void logit_kernel(
    const float* __restrict__ Nm, const float* __restrict__ W1,
    const float* __restrict__ w2, float* __restrict__ logit, int n_nodes) {
  __shared__ float w1t[32 * 129];
  const int tid = threadIdx.x;
  const int j = tid & 127;
  const int half = tid >> 7;
  const int base = blockIdx.x * NPB;
  float acc[8];
#pragma unroll
  for (int g = 0; g < 8; ++g) acc[g] = 0.f;
  for (int c = 0; c < 4; ++c) {
    __syncthreads();
    for (int idx = tid; idx < 128 * 32; idx += 256) {
      int kl = idx & 31, jj = idx >> 5;
      w1t[kl * 129 + jj] = W1[jj * 128 + c * 32 + kl];
    }
    __syncthreads();
#pragma unroll
    for (int g = 0; g < 8; ++g) {
      int node = base + g * 2 + half;
      if (node < n_nodes) {
        const float4* nrow =
            reinterpret_cast<const float4*>(Nm + (size_t)node * D + c * 32);
        float a = acc[g];
#pragma unroll
        for (int k4 = 0; k4 < 8; ++k4) {
          float4 nv = nrow[k4];
          int kl = k4 * 4;
          a += nv.x * w1t[(kl + 0) * 129 + j];
          a += nv.y * w1t[(kl + 1) * 129 + j];
          a += nv.z * w1t[(kl + 2) * 129 + j];
          a += nv.w * w1t[(kl + 3) * 129 + j];
        }
        acc[g] = a;
      }
    }
  }
  const float w2j = w2[j];
#pragma unroll
  for (int g = 0; g < 8; ++g) {
    int node = base + g * 2 + half;
    float t = tanhf(acc[g]) * w2j;
#pragma unroll
    for (int off = 32; off; off >>= 1) t += __shfl_down(t, off);
    if ((tid & 63) == 0 && node < n_nodes) atomicAdd(&logit[node], t);
  }
}

__global__ __launch_bounds__(256) void denom_kernel(
    const int* __restrict__ src, const int* __restrict__ dst,
    const float* __restrict__ logit, float* __restrict__ denom, int n_edges) {
  int e = blockIdx.x * 256 + threadIdx.x;
  if (e < n_edges) {
    float ex = expf(logit[src[e]]);
    atomicAdd(&denom[dst[e]], ex);
  }
}

__global__ __launch_bounds__(256) void scatter_kernel(
    const int* __restrict__ src, const int* __restrict__ dst,
    const float* __restrict__ logit, const float* __restrict__ denom,
    const float* __restrict__ Nm, float* __restrict__ out, int n_edges) {
  int wave = (blockIdx.x * 256 + threadIdx.x) >> 6;
  int lane = threadIdx.x & 63;
  if (wave >= n_edges) return;
  int s = src[wave];
  int d = dst[wave];
  float a = expf(logit[s]) / denom[d];
  float v0 = Nm[(size_t)s * D + lane];
  float v1 = Nm[(size_t)s * D + 64 + lane];
  atomicAdd(&out[(size_t)d * D + lane], a * v0);
  atomicAdd(&out[(size_t)d * D + 64 + lane], a * v1);
}

static inline char* align_up(char* p, size_t a) {
  return (char*)(((uintptr_t)p + a - 1) & ~(uintptr_t)(a - 1));
}

extern "C" void kernel_launch(void* const* d_in, const int* in_sizes, int n_in,
                              void* d_out, int out_size, void* d_ws,
                              size_t ws_size, hipStream_t stream) {
  const float* Nm  = (const float*)d_in[0];
  const float* W1  = (const float*)d_in[1];
  const float* w2  = (const float*)d_in[2];
  const int*   src = (const int*)d_in[3];
  const int*   dst = (const int*)d_in[4];
  float* out = (float*)d_out;

  const int n_nodes = in_sizes[0] / D;
  const int n_edges = in_sizes[3];
  const int n_pad = (n_nodes + 63) & ~63;
  const int nbuck = (n_nodes + BKN - 1) / BKN;
  const int nblk_bin = (n_edges + CHUNK - 1) / CHUNK;

  // carve workspace
  char* p = (char*)d_ws;
  float* explog = (float*)p;     p = align_up(p + (size_t)n_pad * 4, 256);
  float* denomF = (float*)p;     p = align_up(p + (size_t)n_pad * 4, 256);
  unsigned short* nbf = (unsigned short*)p;
  p = align_up(p + (size_t)n_nodes * D * 2, 256);
  unsigned* binout = (unsigned*)p;
  p = align_up(p + (size_t)nblk_bin * CHUNK * 4, 256);
  unsigned short* dir = (unsigned short*)p;
  p = align_up(p + (size_t)nblk_bin * (nbuck + 1) * 2, 256);
  unsigned* sorted = (unsigned*)p;
  p = align_up(p + (size_t)nbuck * CAP * 4, 256);
  int* offsets = (int*)p;        p = align_up(p + (size_t)n_pad * 4, 256);
  int* ends    = (int*)p;        p = align_up(p + (size_t)n_pad * 4, 256);
  size_t needed = (size_t)(p - (char*)d_ws);

  const bool fits = (ws_size >= needed) && (n_nodes <= 65535) &&
                    (nbuck <= MAXBUCK) && (nblk_bin <= NCHUNK_MAX) &&
                    ((n_edges / (nbuck > 0 ? nbuck : 1)) * 3 < CAP);

  if (fits) {
    // logit chain (fused: W1 split + logits + exp + nbf export)
    int nblk1 = (n_nodes + 63) / 64;
    logit_mfma_kernel<<<nblk1, 256, 0, stream>>>(Nm, W1, w2, explog, nbf,
                                                 n_nodes);

    // edge sort: chunk-local bin -> per-bucket merge (private windows)
    bin_kernel<<<nblk_bin, 256, 0, stream>>>(src, dst, binout, dir, n_edges,
                                             nbuck);
    merge_kernel<<<nbuck, 256, 0, stream>>>(binout, dir, sorted, offsets,
                                            ends, n_nodes, nbuck, nblk_bin);

    // accumulation (wave per node, 8-deep vector gather pipeline)
    int ablk = (n_nodes + 3) / 4;
    accum_sorted_kernel<<<ablk, 256, 0, stream>>>(
        offsets, ends, sorted, explog, (const unsigned*)nbf, out, n_nodes);
  } else {
    // fallback: scalar logit + R1 atomic path
    float* logit = explog;
    float* denom = denomF;
    hipMemsetAsync(logit, 0, (size_t)n_pad * sizeof(float), stream);
    hipMemsetAsync(denom, 0, (size_t)n_pad * sizeof(float), stream);
    hipMemsetAsync(out, 0, (size_t)out_size * sizeof(float), stream);
    int nblk1 = (n_nodes + NPB - 1) / NPB;
    logit_kernel<<<nblk1, 256, 0, stream>>>(Nm, W1, w2, logit, n_nodes);
    int eblk = (n_edges + 255) / 256;
    denom_kernel<<<eblk, 256, 0, stream>>>(src, dst, logit, denom, n_edges);
    int nblk3 = (n_edges + 3) / 4;
    scatter_kernel<<<nblk3, 256, 0, stream>>>(src, dst, logit, denom, Nm, out,
                                              n_edges);
  }
}